// Round 15
// baseline (142.172 us; speedup 1.0000x reference)
//
#include <hip/hip_runtime.h>
#include <math.h>

// Margin loss with distance-weighted sampling — expectation form.
// R19: shrink the block. R18 closed XCD-swizzle (neutral: FETCH -2.6MB,
// time unchanged). R14 (131.5us; gram 66 = 36 VALU + 30 stall at 8
// waves/CU) stands. The VGPR-cliff law (R7-R16) killed every same-size
// restructure; the untried direction is SMALLER per-block state:
// 64x64 tiles, 8256 blocks, 4 waves of 32x32 -> acc[2][2]=16 AGPR,
// ts[8], frag regs 16 -> peak ~100/wave; LDS 33.5KB -> 4 blocks/CU =
// 16 waves (2x R14) by demand reduction, not restructure. Costs: 2x
// staging traffic (L2-resident, ~7.6us aggregate) + ~2x fold perimeter.
// P becomes [3][128][8192] (12.6MB, each (row,slot) written once);
// ws-checked with atomic fallback. Same epilogue math, same final.

#define NROWS 8192
#define DDIM  128
#define NPAIRF 7.0f
#define BT 64
#define NTILE (NROWS / BT)                    // 128
#define NPAIRS (NTILE * (NTILE + 1) / 2)      // 8256
#define LW2_SHIFT 57.70780163555852f          // 40 / ln2
#define FINAL_BLOCKS 256

typedef short bf16x8 __attribute__((ext_vector_type(8)));   // 8 bf16 = 4 VGPRs
typedef float f32x4  __attribute__((ext_vector_type(4)));   // MFMA C/D

template <bool B> struct BoolK { static constexpr bool value = B; };

__device__ __forceinline__ unsigned short f2bf(float f) {
    unsigned int u = __float_as_uint(f);
    return (unsigned short)((u + 0x7fffu + ((u >> 16) & 1u)) >> 16);   // RNE
}

// stage one 64x128 tile from f32 x into swizzled bf16 LDS (256 threads):
// 1024 uint4 slots, 4 per thread; phys = row*16 + (kb ^ (row&7)).
__device__ __forceinline__ void stage_from_x(const float* __restrict__ x,
        int base_row, unsigned short* buf, int tid) {
#pragma unroll
    for (int t = 0; t < 4; t++) {
        int s = tid + t * 256;
        int row = s >> 4;               // 0..63
        int kb = s & 15;
        int phys = row * 16 + (kb ^ (row & 7));
        const float4* src = (const float4*)&x[(size_t)(base_row + row) * DDIM + kb * 8];
        float4 v0 = src[0], v1 = src[1];
        uint4 pk;
        pk.x = (unsigned)f2bf(v0.x) | ((unsigned)f2bf(v0.y) << 16);
        pk.y = (unsigned)f2bf(v0.z) | ((unsigned)f2bf(v0.w) << 16);
        pk.z = (unsigned)f2bf(v1.x) | ((unsigned)f2bf(v1.y) << 16);
        pk.w = (unsigned)f2bf(v1.z) | ((unsigned)f2bf(v1.w) << 16);
        ((uint4*)buf)[phys] = pk;
    }
}

// fallback-only: zero rowacc + accum
__global__ void prep_kernel(float* __restrict__ rowacc, float* __restrict__ accum) {
    int t = blockIdx.x * 256 + threadIdx.x;
    if (t < NROWS * 3) rowacc[t] = 0.0f;
    if (t < 8) accum[t] = 0.0f;
}

// One block per unordered 64-tile pair (I <= J). 4 waves, 32x32 wave tiles.
// DET: combined sums stored once to P[3][NTILE][NROWS]; else atomicAdd.
template <bool DET>
__global__ __launch_bounds__(256) void gram_kernel(
        const float* __restrict__ x, const float* __restrict__ beta,
        float* __restrict__ Pout, float* __restrict__ accum) {
    __shared__ unsigned short Abuf[BT * DDIM];   // 16 KB
    __shared__ unsigned short Bbuf[BT * DDIM];   // 16 KB
    __shared__ float comb_rows[BT][3];           // 0.75 KB
    __shared__ float comb_cols[BT][3];           // 0.75 KB

    if (DET && blockIdx.x == 0 && threadIdx.x == 0) accum[2] = 0.0f;  // ticket

    // decode blockIdx -> (I, J), I <= J  (row lengths 128, 127, ..., 1)
    int rem = blockIdx.x, I = 0;
    while (rem >= NTILE - I) { rem -= NTILE - I; ++I; }
    const int J = I + rem;
    const int row0 = I * BT, col0 = J * BT;

    const int tid = threadIdx.x;
    const int lane = tid & 63;
    const int wave = tid >> 6;
    const int wy = wave >> 1, wx = wave & 1;    // 2x2 wave grid of 32x32 tiles
    const int l15 = lane & 15, quad = lane >> 4;

    stage_from_x(x, row0, Abuf, tid);
    stage_from_x(x, col0, Bbuf, tid);

    f32x4 acc[2][2];
#pragma unroll
    for (int i = 0; i < 2; i++)
#pragma unroll
        for (int j = 0; j < 2; j++) acc[i][j] = (f32x4){0.f, 0.f, 0.f, 0.f};

    __syncthreads();

#pragma unroll
    for (int kc = 0; kc < 4; kc++) {
        bf16x8 af[2], bfr[2];
#pragma unroll
        for (int i = 0; i < 2; i++) {
            int ra = wy * 32 + i * 16 + l15;
            int pa = (kc * 4 + quad) ^ (ra & 7);
            af[i] = *(const bf16x8*)&Abuf[(ra * 16 + pa) * 8];
            int rb = wx * 32 + i * 16 + l15;
            int pb = (kc * 4 + quad) ^ (rb & 7);
            bfr[i] = *(const bf16x8*)&Bbuf[(rb * 16 + pb) * 8];
        }
#pragma unroll
        for (int i = 0; i < 2; i++)
#pragma unroll
            for (int j = 0; j < 2; j++)
                acc[i][j] = __builtin_amdgcn_mfma_f32_16x16x32_bf16(
                    af[i], bfr[j], acc[i][j], 0, 0, 0);
    }

    // ---- epilogue ----
    float bpc2[2];
    int cloc2[2];
#pragma unroll
    for (int j = 0; j < 2; j++) {
        int cl = wx * 32 + j * 16 + l15;
        bpc2[j] = beta[col0 + cl] + 0.2f;
        cloc2[j] = cl >> 3;
    }
    float bpm8[8];
    int rloc8[8];
#pragma unroll
    for (int i = 0; i < 2; i++)
#pragma unroll
        for (int reg = 0; reg < 4; reg++) {
            int idx = i * 4 + reg;
            int rl = wy * 32 + i * 16 + quad * 4 + reg;
            bpm8[idx] = beta[row0 + rl] + 0.2f;
            rloc8[idx] = rl >> 3;
        }

    float ts0[8], ts1[8], ts2[8];
    float tc0[2], tc1[2], tc2[2];
#pragma unroll
    for (int k = 0; k < 8; k++) ts0[k] = ts1[k] = ts2[k] = 0.0f;
#pragma unroll
    for (int k = 0; k < 2; k++) tc0[k] = tc1[k] = tc2[k] = 0.0f;

    auto fold = [&](auto diag_c) {
        constexpr bool DIAG = decltype(diag_c)::value;
#pragma unroll
        for (int i = 0; i < 2; i++)
#pragma unroll
            for (int reg = 0; reg < 4; reg++) {
                const int idx = i * 4 + reg;
                const float bpm = bpm8[idx];
#pragma unroll
                for (int j = 0; j < 2; j++) {
                    float g = acc[i][j][reg];
                    float dist2 = fmaxf(fmaf(-2.0f, g, 2.0f), 0.0f);   // sq == 1
                    float d = __builtin_amdgcn_sqrtf(dist2 + 1e-8f);
                    float t = fmaxf(dist2, 0.25f);
                    float u = fmaf(-0.25f, t, 1.0f);
                    // w = 2^(-63*log2 t - 62.5*log2 u - 40/ln2) == e^(lw - 40)
                    float lw2 = fmaf(-63.0f, __builtin_amdgcn_logf(t),
                                fmaf(-62.5f, __builtin_amdgcn_logf(u), -LW2_SHIFT));
                    bool valid = t < 1.96f;
                    if (DIAG) valid = valid && (rloc8[idx] != cloc2[j]);
                    float w = valid ? __builtin_amdgcn_exp2f(lw2) : 0.0f;
                    float nlr = fmaxf(bpm - d, 0.0f);
                    ts0[idx] += w;
                    ts1[idx] = fmaf(w, nlr, ts1[idx]);
                    ts2[idx] += (nlr > 0.0f) ? w : 0.0f;
                    if (!DIAG) {
                        float nlc = fmaxf(bpc2[j] - d, 0.0f);
                        tc0[j] += w;
                        tc1[j] = fmaf(w, nlc, tc1[j]);
                        tc2[j] += (nlc > 0.0f) ? w : 0.0f;
                    }
                }
            }
    };
    if (I == J) fold(BoolK<true>{}); else fold(BoolK<false>{});

    // row fold: reduce 16 column-lanes; owner lane l15==idx (idx 0..7)
    float r0 = 0.f, r1 = 0.f, r2 = 0.f;
#pragma unroll
    for (int idx = 0; idx < 8; idx++) {
        float t0 = ts0[idx], t1 = ts1[idx], t2 = ts2[idx];
#pragma unroll
        for (int off = 1; off < 16; off <<= 1) {
            t0 += __shfl_xor(t0, off);
            t1 += __shfl_xor(t1, off);
            t2 += __shfl_xor(t2, off);
        }
        if (l15 == idx) { r0 = t0; r1 = t1; r2 = t2; }
    }
    const int rowl = wy * 32 + (l15 >> 2) * 16 + quad * 4 + (l15 & 3);  // l15<8

    // col fold: reduce across quad groups; lanes with quad==j (j 0..1) keep
    float c0 = 0.f, c1 = 0.f, c2 = 0.f;
#pragma unroll
    for (int j = 0; j < 2; j++) {
        float t0 = tc0[j], t1 = tc1[j], t2 = tc2[j];
        t0 += __shfl_xor(t0, 16); t1 += __shfl_xor(t1, 16); t2 += __shfl_xor(t2, 16);
        t0 += __shfl_xor(t0, 32); t1 += __shfl_xor(t1, 32); t2 += __shfl_xor(t2, 32);
        if (quad == j) { c0 = t0; c1 = t1; c2 = t2; }
    }
    const int coll = wx * 32 + quad * 16 + l15;                          // quad<2

    // cross-wave combine: wx halves for rows, wy halves for cols
    if (wx == 0 && l15 < 8) {
        comb_rows[rowl][0] = r0; comb_rows[rowl][1] = r1; comb_rows[rowl][2] = r2;
    }
    if (wy == 0 && quad < 2 && I != J) {
        comb_cols[coll][0] = c0; comb_cols[coll][1] = c1; comb_cols[coll][2] = c2;
    }
    __syncthreads();
    if (wx == 1 && l15 < 8) {
        float v0 = r0 + comb_rows[rowl][0];
        float v1 = r1 + comb_rows[rowl][1];
        float v2 = r2 + comb_rows[rowl][2];
        int rg = row0 + rowl;
        if (DET) {
            Pout[(0 * NTILE + J) * NROWS + rg] = v0;
            Pout[(1 * NTILE + J) * NROWS + rg] = v1;
            Pout[(2 * NTILE + J) * NROWS + rg] = v2;
        } else {
            atomicAdd(&Pout[rg * 3 + 0], v0);
            atomicAdd(&Pout[rg * 3 + 1], v1);
            atomicAdd(&Pout[rg * 3 + 2], v2);
        }
    }
    if (wy == 1 && quad < 2 && I != J) {
        float v0 = c0 + comb_cols[coll][0];
        float v1 = c1 + comb_cols[coll][1];
        float v2 = c2 + comb_cols[coll][2];
        int cg = col0 + coll;
        if (DET) {
            Pout[(0 * NTILE + I) * NROWS + cg] = v0;
            Pout[(1 * NTILE + I) * NROWS + cg] = v1;
            Pout[(2 * NTILE + I) * NROWS + cg] = v2;
        } else {
            atomicAdd(&Pout[cg * 3 + 0], v0);
            atomicAdd(&Pout[cg * 3 + 1], v1);
            atomicAdd(&Pout[cg * 3 + 2], v2);
        }
    }
}

// One thread per (anchor i, member p): 256 blocks x 256 thr. Block
// partials to blkpart slots (no zeroing needed); last-ticket block sums.
template <bool DET>
__global__ __launch_bounds__(256) void final_kernel(
        const float* __restrict__ x, const float* __restrict__ beta,
        const float* __restrict__ Pin, float* __restrict__ accum,
        float* __restrict__ blkpart, float* __restrict__ out) {
    __shared__ float sm[8];
    __shared__ bool amLast;
    const int tid = threadIdx.x;
    int t = blockIdx.x * 256 + tid;   // t = i*8 + p
    int i = t >> 3;
    int p = t & 7;
    int j = (i & ~7) + p;
    float betai = beta[i];
    const float4* xi = (const float4*)&x[(size_t)i * DDIM];
    const float4* xj = (const float4*)&x[(size_t)j * DDIM];
    float d2 = 0.0f;
#pragma unroll
    for (int k = 0; k < DDIM / 4; k++) {
        float4 va = xi[k], vb = xj[k];
        float dx = va.x - vb.x, dy = va.y - vb.y;
        float dz = va.z - vb.z, dw = va.w - vb.w;
        d2 = fmaf(dx, dx, fmaf(dy, dy, fmaf(dz, dz, fmaf(dw, dw, d2))));
    }
    float d = __builtin_amdgcn_sqrtf(d2 + 1e-8f);
    float nl = fmaxf(betai - d + 0.2f, 0.0f);
    float fb1 = nl;
    float fb2 = (nl > 0.0f) ? 1.0f : 0.0f;
    float num = 0.f, cnt = 0.f;
    if (j != i) {
        float pl = fmaxf(d - betai + 0.2f, 0.0f);
        num = pl;
        cnt = (pl > 0.0f) ? 1.0f : 0.0f;
    }
    // per-lane slice of the row's expectation sums (128 slots / 8 lanes)
    float a0 = 0.f, a1 = 0.f, a2 = 0.f;
    if (DET) {
#pragma unroll
        for (int k = 0; k < 16; k++) {
            int s = p + k * 8;
            a0 += Pin[(0 * NTILE + s) * NROWS + i];
            a1 += Pin[(1 * NTILE + s) * NROWS + i];
            a2 += Pin[(2 * NTILE + s) * NROWS + i];
        }
    }
    // fold the 8 members of this row
#pragma unroll
    for (int off = 1; off < 8; off <<= 1) {
        num += __shfl_xor(num, off); cnt += __shfl_xor(cnt, off);
        fb1 += __shfl_xor(fb1, off); fb2 += __shfl_xor(fb2, off);
        a0 += __shfl_xor(a0, off);  a1 += __shfl_xor(a1, off);
        a2 += __shfl_xor(a2, off);
    }
    if (p == 0) {
        if (!DET) { a0 = Pin[i * 3 + 0]; a1 = Pin[i * 3 + 1]; a2 = Pin[i * 3 + 2]; }
        if (a0 > 0.0f) {
            num += NPAIRF * a1 / a0;
            cnt += NPAIRF * a2 / a0;
        } else {
            // degenerate row: uniform over all n columns; cross-block nl are all 0
            num += NPAIRF * fb1 / (float)NROWS;
            cnt += NPAIRF * fb2 / (float)NROWS;
        }
    } else {
        num = 0.f; cnt = 0.f;
    }
#pragma unroll
    for (int off = 8; off < 64; off <<= 1) {
        num += __shfl_xor(num, off);
        cnt += __shfl_xor(cnt, off);
    }
    int wv = tid >> 6, ln = tid & 63;
    if (ln == 0) { sm[wv] = num; sm[4 + wv] = cnt; }
    __syncthreads();
    if (tid == 0) {
        float n2 = 0.f, c2 = 0.f;
#pragma unroll
        for (int w = 0; w < 4; w++) { n2 += sm[w]; c2 += sm[4 + w]; }
        blkpart[blockIdx.x * 2 + 0] = n2;
        blkpart[blockIdx.x * 2 + 1] = c2;
        __threadfence();
        amLast = (atomicAdd(&accum[2], 1.0f) == (float)(gridDim.x - 1));
    }
    __syncthreads();
    if (amLast) {
        __threadfence();            // acquire: other blocks' partials visible
        float n = blkpart[tid * 2 + 0];
        float c = blkpart[tid * 2 + 1];
#pragma unroll
        for (int off = 1; off < 64; off <<= 1) {
            n += __shfl_xor(n, off);
            c += __shfl_xor(c, off);
        }
        if (ln == 0) { sm[wv] = n; sm[4 + wv] = c; }
        __syncthreads();
        if (tid == 0) {
            float nn = 0.f, cc = 0.f;
#pragma unroll
            for (int w = 0; w < 4; w++) { nn += sm[w]; cc += sm[4 + w]; }
            out[0] = nn / cc;
            accum[2] = 0.0f;        // self-clean for next replay
        }
    }
}

extern "C" void kernel_launch(void* const* d_in, const int* in_sizes, int n_in,
                              void* d_out, int out_size, void* d_ws, size_t ws_size,
                              hipStream_t stream) {
    const float* x = (const float*)d_in[0];
    const float* beta = (const float*)d_in[2];
    float* out = (float*)d_out;
    float* ws = (float*)d_ws;

    float* accum = ws;                                    // 64 floats ([2]=ticket)
    float* blkpart = ws + 64;                             // 256*2
    float* P = blkpart + FINAL_BLOCKS * 2;                // 3*128*8192 floats

    const size_t det_bytes = (64 + FINAL_BLOCKS * 2
                              + (size_t)3 * NTILE * NROWS) * 4;
    if (ws_size >= det_bytes) {
        gram_kernel<true><<<NPAIRS, 256, 0, stream>>>(x, beta, P, accum);
        final_kernel<true><<<FINAL_BLOCKS, 256, 0, stream>>>(x, beta, P, accum,
                                                             blkpart, out);
    } else {
        // fallback: 3-launch atomic path
        float* rowacc = blkpart + FINAL_BLOCKS * 2;       // 8192*3
        prep_kernel<<<(NROWS * 3 + 255) / 256, 256, 0, stream>>>(rowacc, accum);
        gram_kernel<false><<<NPAIRS, 256, 0, stream>>>(x, beta, rowacc, accum);
        final_kernel<false><<<FINAL_BLOCKS, 256, 0, stream>>>(x, beta, rowacc, accum,
                                                              blkpart, out);
    }
}

// Round 16
// 128.891 us; speedup vs baseline: 1.1030x; 1.1030x over previous
//
#include <hip/hip_runtime.h>
#include <math.h>

// Margin loss with distance-weighted sampling — expectation form.
// R20: cut staging conversion ops on the R14 anchor (131.5us best).
// R19's clean decomposition: epilogue math E~20us, staging+fold
// perimeter S+F~16us, stall ~30us at BT=128. Cheapest VALU cut:
// f2bf is a 4-op manual RNE per value (~28 ops/slot); gfx950's
// v_cvt_pk_bf16_f32 packs 2 floats -> 1 dword RNE in ONE instruction
// (4/slot). Bit-identical output (both ties-to-even, inputs normal).
// Zero structural change -> VGPR-cliff law doesn't apply. Everything
// else byte-identical to R14 (R18's XCD swizzle was neutral, omitted).

#define NROWS 8192
#define DDIM  128
#define NPAIRF 7.0f
#define BT 128
#define NTILE (NROWS / BT)                    // 64
#define NPAIRS (NTILE * (NTILE + 1) / 2)      // 2080
#define LW2_SHIFT 57.70780163555852f          // 40 / ln2
#define FINAL_BLOCKS 256

typedef short bf16x8 __attribute__((ext_vector_type(8)));   // 8 bf16 = 4 VGPRs
typedef float f32x4  __attribute__((ext_vector_type(4)));   // MFMA C/D

template <bool B> struct BoolK { static constexpr bool value = B; };

__device__ __forceinline__ unsigned short f2bf(float f) {
    unsigned int u = __float_as_uint(f);
    return (unsigned short)((u + 0x7fffu + ((u >> 16) & 1u)) >> 16);   // RNE
}

// packed f32x2 -> bf16x2 (RNE), one v_cvt_pk_bf16_f32
__device__ __forceinline__ unsigned int cvt_pk_bf16(float lo, float hi) {
    unsigned int r;
    asm("v_cvt_pk_bf16_f32 %0, %1, %2" : "=v"(r) : "v"(lo), "v"(hi));
    return r;
}

// stage one 128x128 tile from f32 x into swizzled bf16 LDS (256 threads)
__device__ __forceinline__ void stage_from_x(const float* __restrict__ x,
        int base_row, unsigned short* buf, int tid) {
#pragma unroll
    for (int t = 0; t < 8; t++) {
        int s = tid + t * 256;
        int row = s >> 4;
        int kb = s & 15;
        int phys = row * 16 + (kb ^ (row & 7));
        const float4* src = (const float4*)&x[(size_t)(base_row + row) * DDIM + kb * 8];
        float4 v0 = src[0], v1 = src[1];
        uint4 pk;
        pk.x = cvt_pk_bf16(v0.x, v0.y);
        pk.y = cvt_pk_bf16(v0.z, v0.w);
        pk.z = cvt_pk_bf16(v1.x, v1.y);
        pk.w = cvt_pk_bf16(v1.z, v1.w);
        ((uint4*)buf)[phys] = pk;
    }
}

// fallback-only: zero rowacc + accum
__global__ void prep_kernel(float* __restrict__ rowacc, float* __restrict__ accum) {
    int t = blockIdx.x * 256 + threadIdx.x;
    if (t < NROWS * 3) rowacc[t] = 0.0f;
    if (t < 8) accum[t] = 0.0f;
}

// One block per unordered tile pair (I <= J). 4 waves, 64x64 wave tiles.
// DET: combined sums stored once to P[3][NTILE][NROWS]; else atomicAdd.
template <bool DET>
__global__ __launch_bounds__(256, 2) void gram_kernel(
        const float* __restrict__ x, const float* __restrict__ beta,
        float* __restrict__ Pout, float* __restrict__ accum) {
    __shared__ unsigned short Abuf[BT * DDIM];   // 32 KB
    __shared__ unsigned short Bbuf[BT * DDIM];   // 32 KB
    __shared__ float comb_rows[BT][3];           // 1.5 KB
    __shared__ float comb_cols[BT][3];           // 1.5 KB

    if (DET && blockIdx.x == 0 && threadIdx.x == 0) accum[2] = 0.0f;  // ticket

    // decode blockIdx -> (I, J), I <= J  (row lengths 64, 63, ..., 1)
    int rem = blockIdx.x, I = 0;
    while (rem >= NTILE - I) { rem -= NTILE - I; ++I; }
    const int J = I + rem;
    const int row0 = I * BT, col0 = J * BT;

    const int tid = threadIdx.x;
    const int lane = tid & 63;
    const int wave = tid >> 6;
    const int wy = wave >> 1, wx = wave & 1;
    const int l15 = lane & 15, quad = lane >> 4;

    stage_from_x(x, row0, Abuf, tid);
    stage_from_x(x, col0, Bbuf, tid);

    f32x4 acc[4][4];
#pragma unroll
    for (int i = 0; i < 4; i++)
#pragma unroll
        for (int j = 0; j < 4; j++) acc[i][j] = (f32x4){0.f, 0.f, 0.f, 0.f};

    __syncthreads();

#pragma unroll
    for (int kc = 0; kc < 4; kc++) {
        bf16x8 af[4], bfr[4];
#pragma unroll
        for (int i = 0; i < 4; i++) {
            int ra = wy * 64 + i * 16 + l15;
            int pa = (kc * 4 + quad) ^ (ra & 7);
            af[i] = *(const bf16x8*)&Abuf[(ra * 16 + pa) * 8];
            int rb = wx * 64 + i * 16 + l15;
            int pb = (kc * 4 + quad) ^ (rb & 7);
            bfr[i] = *(const bf16x8*)&Bbuf[(rb * 16 + pb) * 8];
        }
#pragma unroll
        for (int i = 0; i < 4; i++)
#pragma unroll
            for (int j = 0; j < 4; j++)
                acc[i][j] = __builtin_amdgcn_mfma_f32_16x16x32_bf16(
                    af[i], bfr[j], acc[i][j], 0, 0, 0);
    }

    // ---- epilogue (R14 body, unchanged) ----
    float bpc4[4];
    int cloc4[4];
#pragma unroll
    for (int j = 0; j < 4; j++) {
        int cl = wx * 64 + j * 16 + l15;
        bpc4[j] = beta[col0 + cl] + 0.2f;
        cloc4[j] = cl >> 3;
    }
    float bpm16[16];
    int rloc16[16];
#pragma unroll
    for (int i = 0; i < 4; i++)
#pragma unroll
        for (int reg = 0; reg < 4; reg++) {
            int idx = i * 4 + reg;
            int rl = wy * 64 + i * 16 + quad * 4 + reg;
            bpm16[idx] = beta[row0 + rl] + 0.2f;
            rloc16[idx] = rl >> 3;
        }

    float ts0[16], ts1[16], ts2[16];
    float tc0[4], tc1[4], tc2[4];
#pragma unroll
    for (int k = 0; k < 16; k++) ts0[k] = ts1[k] = ts2[k] = 0.0f;
#pragma unroll
    for (int k = 0; k < 4; k++) tc0[k] = tc1[k] = tc2[k] = 0.0f;

    auto fold = [&](auto diag_c) {
        constexpr bool DIAG = decltype(diag_c)::value;
#pragma unroll
        for (int i = 0; i < 4; i++)
#pragma unroll
            for (int reg = 0; reg < 4; reg++) {
                const int idx = i * 4 + reg;
                const float bpm = bpm16[idx];
#pragma unroll
                for (int j = 0; j < 4; j++) {
                    float g = acc[i][j][reg];
                    float dist2 = fmaxf(fmaf(-2.0f, g, 2.0f), 0.0f);   // sq == 1
                    float d = __builtin_amdgcn_sqrtf(dist2 + 1e-8f);
                    float t = fmaxf(dist2, 0.25f);
                    float u = fmaf(-0.25f, t, 1.0f);
                    // w = 2^(-63*log2 t - 62.5*log2 u - 40/ln2) == e^(lw - 40)
                    float lw2 = fmaf(-63.0f, __builtin_amdgcn_logf(t),
                                fmaf(-62.5f, __builtin_amdgcn_logf(u), -LW2_SHIFT));
                    bool valid = t < 1.96f;
                    if (DIAG) valid = valid && (rloc16[idx] != cloc4[j]);
                    float w = valid ? __builtin_amdgcn_exp2f(lw2) : 0.0f;
                    float nlr = fmaxf(bpm - d, 0.0f);
                    ts0[idx] += w;
                    ts1[idx] = fmaf(w, nlr, ts1[idx]);
                    ts2[idx] += (nlr > 0.0f) ? w : 0.0f;
                    if (!DIAG) {
                        float nlc = fmaxf(bpc4[j] - d, 0.0f);
                        tc0[j] += w;
                        tc1[j] = fmaf(w, nlc, tc1[j]);
                        tc2[j] += (nlc > 0.0f) ? w : 0.0f;
                    }
                }
            }
    };
    if (I == J) fold(BoolK<true>{}); else fold(BoolK<false>{});

    // row fold: reduce 16 column-lanes; lane l15==idx keeps its row's sums
    float r0 = 0.f, r1 = 0.f, r2 = 0.f;
#pragma unroll
    for (int idx = 0; idx < 16; idx++) {
        float t0 = ts0[idx], t1 = ts1[idx], t2 = ts2[idx];
#pragma unroll
        for (int off = 1; off < 16; off <<= 1) {
            t0 += __shfl_xor(t0, off);
            t1 += __shfl_xor(t1, off);
            t2 += __shfl_xor(t2, off);
        }
        if (l15 == idx) { r0 = t0; r1 = t1; r2 = t2; }
    }
    const int rowl = wy * 64 + (l15 >> 2) * 16 + quad * 4 + (l15 & 3);

    // col fold: reduce across quad groups; lane quad==j keeps col j
    float c0 = 0.f, c1 = 0.f, c2 = 0.f;
#pragma unroll
    for (int j = 0; j < 4; j++) {
        float t0 = tc0[j], t1 = tc1[j], t2 = tc2[j];
        t0 += __shfl_xor(t0, 16); t1 += __shfl_xor(t1, 16); t2 += __shfl_xor(t2, 16);
        t0 += __shfl_xor(t0, 32); t1 += __shfl_xor(t1, 32); t2 += __shfl_xor(t2, 32);
        if (quad == j) { c0 = t0; c1 = t1; c2 = t2; }
    }
    const int coll = wx * 64 + quad * 16 + l15;

    // cross-wave combine: wx halves for rows, wy halves for cols
    if (wx == 0) {
        comb_rows[rowl][0] = r0; comb_rows[rowl][1] = r1; comb_rows[rowl][2] = r2;
    }
    if (wy == 0 && I != J) {
        comb_cols[coll][0] = c0; comb_cols[coll][1] = c1; comb_cols[coll][2] = c2;
    }
    __syncthreads();
    if (wx == 1) {
        float v0 = r0 + comb_rows[rowl][0];
        float v1 = r1 + comb_rows[rowl][1];
        float v2 = r2 + comb_rows[rowl][2];
        int rg = row0 + rowl;
        if (DET) {
            Pout[(0 * NTILE + J) * NROWS + rg] = v0;
            Pout[(1 * NTILE + J) * NROWS + rg] = v1;
            Pout[(2 * NTILE + J) * NROWS + rg] = v2;
        } else {
            atomicAdd(&Pout[rg * 3 + 0], v0);
            atomicAdd(&Pout[rg * 3 + 1], v1);
            atomicAdd(&Pout[rg * 3 + 2], v2);
        }
    }
    if (wy == 1 && I != J) {
        float v0 = c0 + comb_cols[coll][0];
        float v1 = c1 + comb_cols[coll][1];
        float v2 = c2 + comb_cols[coll][2];
        int cg = col0 + coll;
        if (DET) {
            Pout[(0 * NTILE + I) * NROWS + cg] = v0;
            Pout[(1 * NTILE + I) * NROWS + cg] = v1;
            Pout[(2 * NTILE + I) * NROWS + cg] = v2;
        } else {
            atomicAdd(&Pout[cg * 3 + 0], v0);
            atomicAdd(&Pout[cg * 3 + 1], v1);
            atomicAdd(&Pout[cg * 3 + 2], v2);
        }
    }
}

// One thread per (anchor i, member p): 256 blocks x 256 thr. Block
// partials to blkpart slots (no zeroing needed); last-ticket block sums.
template <bool DET>
__global__ __launch_bounds__(256) void final_kernel(
        const float* __restrict__ x, const float* __restrict__ beta,
        const float* __restrict__ Pin, float* __restrict__ accum,
        float* __restrict__ blkpart, float* __restrict__ out) {
    __shared__ float sm[8];
    __shared__ bool amLast;
    const int tid = threadIdx.x;
    int t = blockIdx.x * 256 + tid;   // t = i*8 + p
    int i = t >> 3;
    int p = t & 7;
    int j = (i & ~7) + p;
    float betai = beta[i];
    const float4* xi = (const float4*)&x[(size_t)i * DDIM];
    const float4* xj = (const float4*)&x[(size_t)j * DDIM];
    float d2 = 0.0f;
#pragma unroll
    for (int k = 0; k < DDIM / 4; k++) {
        float4 va = xi[k], vb = xj[k];
        float dx = va.x - vb.x, dy = va.y - vb.y;
        float dz = va.z - vb.z, dw = va.w - vb.w;
        d2 = fmaf(dx, dx, fmaf(dy, dy, fmaf(dz, dz, fmaf(dw, dw, d2))));
    }
    float d = __builtin_amdgcn_sqrtf(d2 + 1e-8f);
    float nl = fmaxf(betai - d + 0.2f, 0.0f);
    float fb1 = nl;
    float fb2 = (nl > 0.0f) ? 1.0f : 0.0f;
    float num = 0.f, cnt = 0.f;
    if (j != i) {
        float pl = fmaxf(d - betai + 0.2f, 0.0f);
        num = pl;
        cnt = (pl > 0.0f) ? 1.0f : 0.0f;
    }
    // per-lane slice of the row's expectation sums
    float a0 = 0.f, a1 = 0.f, a2 = 0.f;
    if (DET) {
#pragma unroll
        for (int k = 0; k < 8; k++) {
            int s = p + k * 8;
            a0 += Pin[(0 * NTILE + s) * NROWS + i];
            a1 += Pin[(1 * NTILE + s) * NROWS + i];
            a2 += Pin[(2 * NTILE + s) * NROWS + i];
        }
    }
    // fold the 8 members of this row
#pragma unroll
    for (int off = 1; off < 8; off <<= 1) {
        num += __shfl_xor(num, off); cnt += __shfl_xor(cnt, off);
        fb1 += __shfl_xor(fb1, off); fb2 += __shfl_xor(fb2, off);
        a0 += __shfl_xor(a0, off);  a1 += __shfl_xor(a1, off);
        a2 += __shfl_xor(a2, off);
    }
    if (p == 0) {
        if (!DET) { a0 = Pin[i * 3 + 0]; a1 = Pin[i * 3 + 1]; a2 = Pin[i * 3 + 2]; }
        if (a0 > 0.0f) {
            num += NPAIRF * a1 / a0;
            cnt += NPAIRF * a2 / a0;
        } else {
            // degenerate row: uniform over all n columns; cross-block nl are all 0
            num += NPAIRF * fb1 / (float)NROWS;
            cnt += NPAIRF * fb2 / (float)NROWS;
        }
    } else {
        num = 0.f; cnt = 0.f;
    }
#pragma unroll
    for (int off = 8; off < 64; off <<= 1) {
        num += __shfl_xor(num, off);
        cnt += __shfl_xor(cnt, off);
    }
    int wv = tid >> 6, ln = tid & 63;
    if (ln == 0) { sm[wv] = num; sm[4 + wv] = cnt; }
    __syncthreads();
    if (tid == 0) {
        float n2 = 0.f, c2 = 0.f;
#pragma unroll
        for (int w = 0; w < 4; w++) { n2 += sm[w]; c2 += sm[4 + w]; }
        blkpart[blockIdx.x * 2 + 0] = n2;
        blkpart[blockIdx.x * 2 + 1] = c2;
        __threadfence();
        amLast = (atomicAdd(&accum[2], 1.0f) == (float)(gridDim.x - 1));
    }
    __syncthreads();
    if (amLast) {
        __threadfence();            // acquire: other blocks' partials visible
        float n = blkpart[tid * 2 + 0];
        float c = blkpart[tid * 2 + 1];
#pragma unroll
        for (int off = 1; off < 64; off <<= 1) {
            n += __shfl_xor(n, off);
            c += __shfl_xor(c, off);
        }
        if (ln == 0) { sm[wv] = n; sm[4 + wv] = c; }
        __syncthreads();
        if (tid == 0) {
            float nn = 0.f, cc = 0.f;
#pragma unroll
            for (int w = 0; w < 4; w++) { nn += sm[w]; cc += sm[4 + w]; }
            out[0] = nn / cc;
            accum[2] = 0.0f;        // self-clean for next replay
        }
    }
}

extern "C" void kernel_launch(void* const* d_in, const int* in_sizes, int n_in,
                              void* d_out, int out_size, void* d_ws, size_t ws_size,
                              hipStream_t stream) {
    const float* x = (const float*)d_in[0];
    const float* beta = (const float*)d_in[2];
    float* out = (float*)d_out;
    float* ws = (float*)d_ws;

    float* accum = ws;                                    // 64 floats ([2]=ticket)
    float* blkpart = ws + 64;                             // 256*2
    float* P = blkpart + FINAL_BLOCKS * 2;                // 3*64*8192 floats

    const size_t det_bytes = (64 + FINAL_BLOCKS * 2
                              + (size_t)3 * NTILE * NROWS) * 4;
    if (ws_size >= det_bytes) {
        gram_kernel<true><<<NPAIRS, 256, 0, stream>>>(x, beta, P, accum);
        final_kernel<true><<<FINAL_BLOCKS, 256, 0, stream>>>(x, beta, P, accum,
                                                             blkpart, out);
    } else {
        // fallback: 3-launch atomic path
        float* rowacc = blkpart + FINAL_BLOCKS * 2;       // 8192*3
        prep_kernel<<<(NROWS * 3 + 255) / 256, 256, 0, stream>>>(rowacc, accum);
        gram_kernel<false><<<NPAIRS, 256, 0, stream>>>(x, beta, rowacc, accum);
        final_kernel<false><<<FINAL_BLOCKS, 256, 0, stream>>>(x, beta, rowacc, accum,
                                                              blkpart, out);
    }
}

// Round 17
// 122.894 us; speedup vs baseline: 1.1569x; 1.0488x over previous
//
#include <hip/hip_runtime.h>
#include <math.h>

// Margin loss with distance-weighted sampling — expectation form.
// R21: butterfly folds on the R20 anchor (128.9us best; gram 62.6).
// R20 proved expression-local changes don't trip the VGPR cliff
// (cvt_pk: -3.3us, VGPR held 128). The fold is the next throughput
// item: 16 sequential 4-step shfl chains = ~1200 VALU ops/thread
// (~6-8us of gram). Pair-merge butterfly computes the same 16 row
// sums in 15 merges (~180 ops): after steps off=8,4,2,1, slot 0 on
// lane l15 holds row l15 (row = 8b3+4b2+2b1+b0); col fold via
// off=32,16 leaves col==quad on slot 0. Everything else byte-identical
// to R20. Gates: VGPR==128, absmax <= 2e-3 (f32 tree-order change).

#define NROWS 8192
#define DDIM  128
#define NPAIRF 7.0f
#define BT 128
#define NTILE (NROWS / BT)                    // 64
#define NPAIRS (NTILE * (NTILE + 1) / 2)      // 2080
#define LW2_SHIFT 57.70780163555852f          // 40 / ln2
#define FINAL_BLOCKS 256

typedef short bf16x8 __attribute__((ext_vector_type(8)));   // 8 bf16 = 4 VGPRs
typedef float f32x4  __attribute__((ext_vector_type(4)));   // MFMA C/D

template <bool B> struct BoolK { static constexpr bool value = B; };

// packed f32x2 -> bf16x2 (RNE), one v_cvt_pk_bf16_f32
__device__ __forceinline__ unsigned int cvt_pk_bf16(float lo, float hi) {
    unsigned int r;
    asm("v_cvt_pk_bf16_f32 %0, %1, %2" : "=v"(r) : "v"(lo), "v"(hi));
    return r;
}

// stage one 128x128 tile from f32 x into swizzled bf16 LDS (256 threads)
__device__ __forceinline__ void stage_from_x(const float* __restrict__ x,
        int base_row, unsigned short* buf, int tid) {
#pragma unroll
    for (int t = 0; t < 8; t++) {
        int s = tid + t * 256;
        int row = s >> 4;
        int kb = s & 15;
        int phys = row * 16 + (kb ^ (row & 7));
        const float4* src = (const float4*)&x[(size_t)(base_row + row) * DDIM + kb * 8];
        float4 v0 = src[0], v1 = src[1];
        uint4 pk;
        pk.x = cvt_pk_bf16(v0.x, v0.y);
        pk.y = cvt_pk_bf16(v0.z, v0.w);
        pk.z = cvt_pk_bf16(v1.x, v1.y);
        pk.w = cvt_pk_bf16(v1.z, v1.w);
        ((uint4*)buf)[phys] = pk;
    }
}

// fallback-only: zero rowacc + accum
__global__ void prep_kernel(float* __restrict__ rowacc, float* __restrict__ accum) {
    int t = blockIdx.x * 256 + threadIdx.x;
    if (t < NROWS * 3) rowacc[t] = 0.0f;
    if (t < 8) accum[t] = 0.0f;
}

// One block per unordered tile pair (I <= J). 4 waves, 64x64 wave tiles.
// DET: combined sums stored once to P[3][NTILE][NROWS]; else atomicAdd.
template <bool DET>
__global__ __launch_bounds__(256, 2) void gram_kernel(
        const float* __restrict__ x, const float* __restrict__ beta,
        float* __restrict__ Pout, float* __restrict__ accum) {
    __shared__ unsigned short Abuf[BT * DDIM];   // 32 KB
    __shared__ unsigned short Bbuf[BT * DDIM];   // 32 KB
    __shared__ float comb_rows[BT][3];           // 1.5 KB
    __shared__ float comb_cols[BT][3];           // 1.5 KB

    if (DET && blockIdx.x == 0 && threadIdx.x == 0) accum[2] = 0.0f;  // ticket

    // decode blockIdx -> (I, J), I <= J  (row lengths 64, 63, ..., 1)
    int rem = blockIdx.x, I = 0;
    while (rem >= NTILE - I) { rem -= NTILE - I; ++I; }
    const int J = I + rem;
    const int row0 = I * BT, col0 = J * BT;

    const int tid = threadIdx.x;
    const int lane = tid & 63;
    const int wave = tid >> 6;
    const int wy = wave >> 1, wx = wave & 1;
    const int l15 = lane & 15, quad = lane >> 4;

    stage_from_x(x, row0, Abuf, tid);
    stage_from_x(x, col0, Bbuf, tid);

    f32x4 acc[4][4];
#pragma unroll
    for (int i = 0; i < 4; i++)
#pragma unroll
        for (int j = 0; j < 4; j++) acc[i][j] = (f32x4){0.f, 0.f, 0.f, 0.f};

    __syncthreads();

#pragma unroll
    for (int kc = 0; kc < 4; kc++) {
        bf16x8 af[4], bfr[4];
#pragma unroll
        for (int i = 0; i < 4; i++) {
            int ra = wy * 64 + i * 16 + l15;
            int pa = (kc * 4 + quad) ^ (ra & 7);
            af[i] = *(const bf16x8*)&Abuf[(ra * 16 + pa) * 8];
            int rb = wx * 64 + i * 16 + l15;
            int pb = (kc * 4 + quad) ^ (rb & 7);
            bfr[i] = *(const bf16x8*)&Bbuf[(rb * 16 + pb) * 8];
        }
#pragma unroll
        for (int i = 0; i < 4; i++)
#pragma unroll
            for (int j = 0; j < 4; j++)
                acc[i][j] = __builtin_amdgcn_mfma_f32_16x16x32_bf16(
                    af[i], bfr[j], acc[i][j], 0, 0, 0);
    }

    // ---- epilogue (R14/R20 body, unchanged) ----
    float bpc4[4];
    int cloc4[4];
#pragma unroll
    for (int j = 0; j < 4; j++) {
        int cl = wx * 64 + j * 16 + l15;
        bpc4[j] = beta[col0 + cl] + 0.2f;
        cloc4[j] = cl >> 3;
    }
    float bpm16[16];
    int rloc16[16];
#pragma unroll
    for (int i = 0; i < 4; i++)
#pragma unroll
        for (int reg = 0; reg < 4; reg++) {
            int idx = i * 4 + reg;
            int rl = wy * 64 + i * 16 + quad * 4 + reg;
            bpm16[idx] = beta[row0 + rl] + 0.2f;
            rloc16[idx] = rl >> 3;
        }

    float ts0[16], ts1[16], ts2[16];
    float tc0[4], tc1[4], tc2[4];
#pragma unroll
    for (int k = 0; k < 16; k++) ts0[k] = ts1[k] = ts2[k] = 0.0f;
#pragma unroll
    for (int k = 0; k < 4; k++) tc0[k] = tc1[k] = tc2[k] = 0.0f;

    auto fold = [&](auto diag_c) {
        constexpr bool DIAG = decltype(diag_c)::value;
#pragma unroll
        for (int i = 0; i < 4; i++)
#pragma unroll
            for (int reg = 0; reg < 4; reg++) {
                const int idx = i * 4 + reg;
                const float bpm = bpm16[idx];
#pragma unroll
                for (int j = 0; j < 4; j++) {
                    float g = acc[i][j][reg];
                    float dist2 = fmaxf(fmaf(-2.0f, g, 2.0f), 0.0f);   // sq == 1
                    float d = __builtin_amdgcn_sqrtf(dist2 + 1e-8f);
                    float t = fmaxf(dist2, 0.25f);
                    float u = fmaf(-0.25f, t, 1.0f);
                    // w = 2^(-63*log2 t - 62.5*log2 u - 40/ln2) == e^(lw - 40)
                    float lw2 = fmaf(-63.0f, __builtin_amdgcn_logf(t),
                                fmaf(-62.5f, __builtin_amdgcn_logf(u), -LW2_SHIFT));
                    bool valid = t < 1.96f;
                    if (DIAG) valid = valid && (rloc16[idx] != cloc4[j]);
                    float w = valid ? __builtin_amdgcn_exp2f(lw2) : 0.0f;
                    float nlr = fmaxf(bpm - d, 0.0f);
                    ts0[idx] += w;
                    ts1[idx] = fmaf(w, nlr, ts1[idx]);
                    ts2[idx] += (nlr > 0.0f) ? w : 0.0f;
                    if (!DIAG) {
                        float nlc = fmaxf(bpc4[j] - d, 0.0f);
                        tc0[j] += w;
                        tc1[j] = fmaf(w, nlc, tc1[j]);
                        tc2[j] += (nlc > 0.0f) ? w : 0.0f;
                    }
                }
            }
    };
    if (I == J) fold(BoolK<true>{}); else fold(BoolK<false>{});

    // row fold: pair-merge butterfly. After steps off=8,4,2,1 slot 0 on
    // lane l15 holds the 16-lane sum for row == l15 (row = 8b3+4b2+2b1+b0).
#pragma unroll
    for (int off = 8; off >= 1; off >>= 1) {
#pragma unroll
        for (int i = 0; i < 8; i++) {
            if (i >= off) continue;
            const bool hi = (l15 & off) != 0;
            float a0 = ts0[i], b0 = ts0[i + off];
            float a1 = ts1[i], b1 = ts1[i + off];
            float a2 = ts2[i], b2 = ts2[i + off];
            float g0 = __shfl_xor(hi ? a0 : b0, off);
            float g1 = __shfl_xor(hi ? a1 : b1, off);
            float g2 = __shfl_xor(hi ? a2 : b2, off);
            ts0[i] = (hi ? b0 : a0) + g0;
            ts1[i] = (hi ? b1 : a1) + g1;
            ts2[i] = (hi ? b2 : a2) + g2;
        }
    }
    const float r0 = ts0[0], r1 = ts1[0], r2 = ts2[0];
    const int rowl = wy * 64 + (l15 >> 2) * 16 + quad * 4 + (l15 & 3);

    // col fold: butterfly across quad groups (off=32 then 16); slot 0 on
    // lanes with quad==q holds col q (col = 2*b5 + b4).
#pragma unroll
    for (int off = 32; off >= 16; off >>= 1) {
        const int n = off >> 4;             // 2 then 1
#pragma unroll
        for (int i = 0; i < 2; i++) {
            if (i >= n) continue;
            const bool hi = (lane & off) != 0;
            float a0 = tc0[i], b0 = tc0[i + n];
            float a1 = tc1[i], b1 = tc1[i + n];
            float a2 = tc2[i], b2 = tc2[i + n];
            float g0 = __shfl_xor(hi ? a0 : b0, off);
            float g1 = __shfl_xor(hi ? a1 : b1, off);
            float g2 = __shfl_xor(hi ? a2 : b2, off);
            tc0[i] = (hi ? b0 : a0) + g0;
            tc1[i] = (hi ? b1 : a1) + g1;
            tc2[i] = (hi ? b2 : a2) + g2;
        }
    }
    const float c0 = tc0[0], c1 = tc1[0], c2 = tc2[0];
    const int coll = wx * 64 + quad * 16 + l15;

    // cross-wave combine: wx halves for rows, wy halves for cols
    if (wx == 0) {
        comb_rows[rowl][0] = r0; comb_rows[rowl][1] = r1; comb_rows[rowl][2] = r2;
    }
    if (wy == 0 && I != J) {
        comb_cols[coll][0] = c0; comb_cols[coll][1] = c1; comb_cols[coll][2] = c2;
    }
    __syncthreads();
    if (wx == 1) {
        float v0 = r0 + comb_rows[rowl][0];
        float v1 = r1 + comb_rows[rowl][1];
        float v2 = r2 + comb_rows[rowl][2];
        int rg = row0 + rowl;
        if (DET) {
            Pout[(0 * NTILE + J) * NROWS + rg] = v0;
            Pout[(1 * NTILE + J) * NROWS + rg] = v1;
            Pout[(2 * NTILE + J) * NROWS + rg] = v2;
        } else {
            atomicAdd(&Pout[rg * 3 + 0], v0);
            atomicAdd(&Pout[rg * 3 + 1], v1);
            atomicAdd(&Pout[rg * 3 + 2], v2);
        }
    }
    if (wy == 1 && I != J) {
        float v0 = c0 + comb_cols[coll][0];
        float v1 = c1 + comb_cols[coll][1];
        float v2 = c2 + comb_cols[coll][2];
        int cg = col0 + coll;
        if (DET) {
            Pout[(0 * NTILE + I) * NROWS + cg] = v0;
            Pout[(1 * NTILE + I) * NROWS + cg] = v1;
            Pout[(2 * NTILE + I) * NROWS + cg] = v2;
        } else {
            atomicAdd(&Pout[cg * 3 + 0], v0);
            atomicAdd(&Pout[cg * 3 + 1], v1);
            atomicAdd(&Pout[cg * 3 + 2], v2);
        }
    }
}

// One thread per (anchor i, member p): 256 blocks x 256 thr. Block
// partials to blkpart slots (no zeroing needed); last-ticket block sums.
template <bool DET>
__global__ __launch_bounds__(256) void final_kernel(
        const float* __restrict__ x, const float* __restrict__ beta,
        const float* __restrict__ Pin, float* __restrict__ accum,
        float* __restrict__ blkpart, float* __restrict__ out) {
    __shared__ float sm[8];
    __shared__ bool amLast;
    const int tid = threadIdx.x;
    int t = blockIdx.x * 256 + tid;   // t = i*8 + p
    int i = t >> 3;
    int p = t & 7;
    int j = (i & ~7) + p;
    float betai = beta[i];
    const float4* xi = (const float4*)&x[(size_t)i * DDIM];
    const float4* xj = (const float4*)&x[(size_t)j * DDIM];
    float d2 = 0.0f;
#pragma unroll
    for (int k = 0; k < DDIM / 4; k++) {
        float4 va = xi[k], vb = xj[k];
        float dx = va.x - vb.x, dy = va.y - vb.y;
        float dz = va.z - vb.z, dw = va.w - vb.w;
        d2 = fmaf(dx, dx, fmaf(dy, dy, fmaf(dz, dz, fmaf(dw, dw, d2))));
    }
    float d = __builtin_amdgcn_sqrtf(d2 + 1e-8f);
    float nl = fmaxf(betai - d + 0.2f, 0.0f);
    float fb1 = nl;
    float fb2 = (nl > 0.0f) ? 1.0f : 0.0f;
    float num = 0.f, cnt = 0.f;
    if (j != i) {
        float pl = fmaxf(d - betai + 0.2f, 0.0f);
        num = pl;
        cnt = (pl > 0.0f) ? 1.0f : 0.0f;
    }
    // per-lane slice of the row's expectation sums
    float a0 = 0.f, a1 = 0.f, a2 = 0.f;
    if (DET) {
#pragma unroll
        for (int k = 0; k < 8; k++) {
            int s = p + k * 8;
            a0 += Pin[(0 * NTILE + s) * NROWS + i];
            a1 += Pin[(1 * NTILE + s) * NROWS + i];
            a2 += Pin[(2 * NTILE + s) * NROWS + i];
        }
    }
    // fold the 8 members of this row
#pragma unroll
    for (int off = 1; off < 8; off <<= 1) {
        num += __shfl_xor(num, off); cnt += __shfl_xor(cnt, off);
        fb1 += __shfl_xor(fb1, off); fb2 += __shfl_xor(fb2, off);
        a0 += __shfl_xor(a0, off);  a1 += __shfl_xor(a1, off);
        a2 += __shfl_xor(a2, off);
    }
    if (p == 0) {
        if (!DET) { a0 = Pin[i * 3 + 0]; a1 = Pin[i * 3 + 1]; a2 = Pin[i * 3 + 2]; }
        if (a0 > 0.0f) {
            num += NPAIRF * a1 / a0;
            cnt += NPAIRF * a2 / a0;
        } else {
            // degenerate row: uniform over all n columns; cross-block nl are all 0
            num += NPAIRF * fb1 / (float)NROWS;
            cnt += NPAIRF * fb2 / (float)NROWS;
        }
    } else {
        num = 0.f; cnt = 0.f;
    }
#pragma unroll
    for (int off = 8; off < 64; off <<= 1) {
        num += __shfl_xor(num, off);
        cnt += __shfl_xor(cnt, off);
    }
    int wv = tid >> 6, ln = tid & 63;
    if (ln == 0) { sm[wv] = num; sm[4 + wv] = cnt; }
    __syncthreads();
    if (tid == 0) {
        float n2 = 0.f, c2 = 0.f;
#pragma unroll
        for (int w = 0; w < 4; w++) { n2 += sm[w]; c2 += sm[4 + w]; }
        blkpart[blockIdx.x * 2 + 0] = n2;
        blkpart[blockIdx.x * 2 + 1] = c2;
        __threadfence();
        amLast = (atomicAdd(&accum[2], 1.0f) == (float)(gridDim.x - 1));
    }
    __syncthreads();
    if (amLast) {
        __threadfence();            // acquire: other blocks' partials visible
        float n = blkpart[tid * 2 + 0];
        float c = blkpart[tid * 2 + 1];
#pragma unroll
        for (int off = 1; off < 64; off <<= 1) {
            n += __shfl_xor(n, off);
            c += __shfl_xor(c, off);
        }
        if (ln == 0) { sm[wv] = n; sm[4 + wv] = c; }
        __syncthreads();
        if (tid == 0) {
            float nn = 0.f, cc = 0.f;
#pragma unroll
            for (int w = 0; w < 4; w++) { nn += sm[w]; cc += sm[4 + w]; }
            out[0] = nn / cc;
            accum[2] = 0.0f;        // self-clean for next replay
        }
    }
}

extern "C" void kernel_launch(void* const* d_in, const int* in_sizes, int n_in,
                              void* d_out, int out_size, void* d_ws, size_t ws_size,
                              hipStream_t stream) {
    const float* x = (const float*)d_in[0];
    const float* beta = (const float*)d_in[2];
    float* out = (float*)d_out;
    float* ws = (float*)d_ws;

    float* accum = ws;                                    // 64 floats ([2]=ticket)
    float* blkpart = ws + 64;                             // 256*2
    float* P = blkpart + FINAL_BLOCKS * 2;                // 3*64*8192 floats

    const size_t det_bytes = (64 + FINAL_BLOCKS * 2
                              + (size_t)3 * NTILE * NROWS) * 4;
    if (ws_size >= det_bytes) {
        gram_kernel<true><<<NPAIRS, 256, 0, stream>>>(x, beta, P, accum);
        final_kernel<true><<<FINAL_BLOCKS, 256, 0, stream>>>(x, beta, P, accum,
                                                             blkpart, out);
    } else {
        // fallback: 3-launch atomic path
        float* rowacc = blkpart + FINAL_BLOCKS * 2;       // 8192*3
        prep_kernel<<<(NROWS * 3 + 255) / 256, 256, 0, stream>>>(rowacc, accum);
        gram_kernel<false><<<NPAIRS, 256, 0, stream>>>(x, beta, rowacc, accum);
        final_kernel<false><<<FINAL_BLOCKS, 256, 0, stream>>>(x, beta, rowacc, accum,
                                                              blkpart, out);
    }
}